// Round 8
// baseline (6192.761 us; speedup 1.0000x reference)
//
#include <hip/hip_runtime.h>

// Problem constants
#define BATCH 256
#define TT    64
#define HH    256
#define DD    8

// Tiling: 2 stacks * 64 batch-blocks of BW=4 -> 128 WGs, 1024 thr (16 waves)
// Round 8: round-7 mechanism (chunk-major weights, global_load_lds 2-deep LDS
// ring, counted vmcnt, raw barrier pairs) restructured for safety:
//  - four uniform 8-chunk loops (W1 / W2I / W2H / B3, then B4) with epilogues
//    BETWEEN loops (no __syncthreads inside unrolled loops)
//  - A-operands read per-chunk from LDS (VGPR ~70, no spill risk at 1024 thr)
//  - received cached in LDS (xv_s) so counted vmcnt waits see only staging ops
//  - store-adjusted wait counts where epilogue global stores enter the queue
#define BW    4
#define NTHR  1024
#define NBLK  (2 * (BATCH / BW))

#define CH48  24576   // elems per 48KB chunk (W1/W2I/W2H)
#define CH32  16384   // elems per 32KB chunk (B3/B4)

typedef __attribute__((ext_vector_type(8))) short bfrag;   // 8 bf16 (MFMA A/B operand)
typedef __attribute__((ext_vector_type(4))) float f4;      // MFMA C/D
typedef __attribute__((ext_vector_type(4))) unsigned int uv4;

#define SWZ(g) ((((g) & 31) << 3) | ((g) >> 5))

__device__ __forceinline__ float rcpf(float x) { return __builtin_amdgcn_rcpf(x); }
__device__ __forceinline__ float sigf(float x) { return rcpf(1.0f + __expf(-x)); }
__device__ __forceinline__ float tanh_fast(float x) {
  const float e = __expf(-2.0f * x);
  return __builtin_fmaf(2.0f, rcpf(1.0f + e), -1.0f);
}
__device__ __forceinline__ unsigned short f2bf(float f) {
  union { float f; unsigned int u; } v; v.f = f;
  return (unsigned short)((v.u + 0x7fffu + ((v.u >> 16) & 1u)) >> 16);
}
__device__ __forceinline__ float bf_lo(unsigned int u) {
  union { unsigned int u; float f; } v; v.u = u << 16; return v.f;
}
__device__ __forceinline__ float bf_hi(unsigned int u) {
  union { unsigned int u; float f; } v; v.u = u & 0xffff0000u; return v.f;
}
__device__ __forceinline__ bfrag zero_frag() {
  bfrag r;
#pragma unroll
  for (int x = 0; x < 8; x++) r[x] = 0;
  return r;
}
__device__ __forceinline__ f4 mfma16(bfrag a, bfrag b, f4 c) {
  return __builtin_amdgcn_mfma_f32_16x16x32_bf16(a, b, c, 0, 0, 0);
}

// counted vmem wait (all call sites compile-time after unrolling)
__device__ __forceinline__ void wait_vm(int n) {
  if (n == 0)      asm volatile("s_waitcnt vmcnt(0)" ::: "memory");
  else if (n == 2) asm volatile("s_waitcnt vmcnt(2)" ::: "memory");
  else if (n == 3) asm volatile("s_waitcnt vmcnt(3)" ::: "memory");
  else if (n == 6) asm volatile("s_waitcnt vmcnt(6)" ::: "memory");
  else             asm volatile("s_waitcnt vmcnt(7)" ::: "memory");
  __builtin_amdgcn_sched_barrier(0);
}
// release barrier: LDS reads retired, then barrier (buffer may be re-staged after)
__device__ __forceinline__ void lds_release_bar() {
  asm volatile("s_waitcnt lgkmcnt(0)" ::: "memory");
  __builtin_amdgcn_sched_barrier(0);
  __builtin_amdgcn_s_barrier();
  __builtin_amdgcn_sched_barrier(0);
}

// ---- async global->LDS staging (16B per lane; LDS dest = uniform base + lane*16)
__device__ __forceinline__ void gl_lds16(const unsigned short* g, unsigned short* l) {
  __builtin_amdgcn_global_load_lds(
      (const __attribute__((address_space(1))) unsigned int*)g,
      (__attribute__((address_space(3))) unsigned int*)l, 16, 0, 0);
}
// 48KB chunk: 3 loads/wave (3KB/wave region)
__device__ __forceinline__ void stage48(const unsigned short* g, unsigned short* l,
                                        int wave, int lane) {
#pragma unroll
  for (int r = 0; r < 3; ++r)
    gl_lds16(g + wave * 1536 + r * 512 + lane * 8, l + wave * 1536 + r * 512);
}
// 32KB chunk: 2 loads/wave (2KB/wave region)
__device__ __forceinline__ void stage32(const unsigned short* g, unsigned short* l,
                                        int wave, int lane) {
#pragma unroll
  for (int r = 0; r < 2; ++r)
    gl_lds16(g + wave * 1024 + r * 512 + lane * 8, l + wave * 1024 + r * 512);
}

// ---------- weight fragment layout (chunk-major, as round 7) ----------
// Stack region (per s): 24 chunks of CH48: m(W1,W2I,W2H) major, then c(0..7),
//   within chunk: [w 0..15][g 0..2][lane 0..63][j 0..7]
// B3: 8 chunks of CH32: [c][t 0..31][lane][j]
// B4: 8 chunks of CH32: [cc][w 0..15][c2 0..1][lane][j], c = cc*2+c2
#define W1_ELEMS  196608
#define STACK_W   (3 * W1_ELEMS)
#define B3_OFF    (2 * STACK_W)
#define B4_OFF    (B3_OFF + 131072)
#define WF_TOTAL  (B4_OFF + 131072)

__global__ __launch_bounds__(256) void prep_weights(
    const float* __restrict__ g1_Whh0, const float* __restrict__ g1_Wih1, const float* __restrict__ g1_Whh1,
    const float* __restrict__ g2_Whh0, const float* __restrict__ g2_Wih1, const float* __restrict__ g2_Whh1,
    const float* __restrict__ attn_W, const float* __restrict__ fc_W,
    unsigned short* __restrict__ wf) {
  const int id = blockIdx.x * 256 + threadIdx.x;
  if (id >= WF_TOTAL) return;
  float src;
  if (id < 2 * STACK_W) {
    const int s = id / STACK_W, r = id % STACK_W;
    const int mm = r / W1_ELEMS, e = r % W1_ELEMS;
    const int c = e / CH48, e2 = e % CH48;
    const int wg = e2 >> 9, l8 = e2 & 511;
    const int w = wg / 3, g = wg % 3;
    const int lane = l8 >> 3, j = l8 & 7;
    const int n = w * 16 + (lane & 15);
    const int k = c * 32 + ((lane >> 4) << 3) + j;
    const float* W = (mm == 0) ? (s ? g2_Whh0 : g1_Whh0)
                   : (mm == 1) ? (s ? g2_Wih1 : g1_Wih1)
                               : (s ? g2_Whh1 : g1_Whh1);
    src = W[(g * 256 + n) * 256 + k];
  } else if (id < B4_OFF) {
    const int e = id - B3_OFF;
    const int c = e / CH32, e2 = e % CH32;
    const int t = e2 >> 9, l8 = e2 & 511;
    const int lane = l8 >> 3, j = l8 & 7;
    const int n = t * 16 + (lane & 15);
    const int k = c * 32 + ((lane >> 4) << 3) + j;
    src = (n < 256) ? attn_W[n * 512 + k] : attn_W[(n - 256) * 512 + 256 + k];
  } else {
    const int e = id - B4_OFF;
    const int cc = e / CH32, e2 = e % CH32;
    const int w = e2 >> 10, c2 = (e2 >> 9) & 1, l8 = e2 & 511;
    const int lane = l8 >> 3, j = l8 & 7;
    const int c = cc * 2 + c2;
    const int n = w * 16 + (lane & 15);
    const int k = c * 32 + ((lane >> 4) << 3) + j;
    src = fc_W[n * 512 + k];
  }
  wf[id] = f2bf(src);
}

__global__ __launch_bounds__(NTHR) void gru_attn(
    const float* __restrict__ received,
    const float* __restrict__ g1_Wih0, const float* __restrict__ g1_bih0, const float* __restrict__ g1_bhh0,
    const float* __restrict__ g1_bih1, const float* __restrict__ g1_bhh1,
    const float* __restrict__ g2_Wih0, const float* __restrict__ g2_bih0, const float* __restrict__ g2_bhh0,
    const float* __restrict__ g2_bih1, const float* __restrict__ g2_bhh1,
    const float* __restrict__ fc_b, const float* __restrict__ v_W, const float* __restrict__ out_W,
    const unsigned short* __restrict__ wf,
    unsigned short* __restrict__ buf_g, unsigned short* __restrict__ ehb_g,
    float* __restrict__ ws_p) {
  const int tid  = threadIdx.x;
  const int lane = tid & 63, wave = tid >> 6;      // 16 waves
  const int col  = lane & 15, q = lane >> 4;
  const int s    = blockIdx.x & 1;                 // stack parity -> XCD parity
  const int b0   = (blockIdx.x >> 1) * BW;

  const float* Wih0 = s ? g2_Wih0 : g1_Wih0;
  const float* bih0 = s ? g2_bih0 : g1_bih0;
  const float* bhh0 = s ? g2_bhh0 : g1_bhh0;
  const float* bih1 = s ? g2_bih1 : g1_bih1;
  const float* bhh1 = s ? g2_bhh1 : g1_bhh1;

  const unsigned short* SR = wf + (size_t)s * STACK_W;   // 24 CH48 chunks
  const unsigned short* B3 = wf + B3_OFF;                // 8 CH32 chunks
  const unsigned short* B4 = wf + B4_OFF;                // 8 CH32 chunks

  unsigned short* buf = buf_g + (size_t)s * BATCH * TT * 2 * HH;
  unsigned short* ehb = ehb_g + (size_t)s * BATCH * TT * 2 * HH;
  float* pp = ws_p + (size_t)s * BATCH * TT;

  // Per-lane persistent constants: each wave owns ONE 16-output group nm = wave*16+col
  const int nm0 = wave * 16 + col;
  const float wxr0 = Wih0[nm0 * 2],         wxr1 = Wih0[nm0 * 2 + 1];
  const float wxz0 = Wih0[(256 + nm0) * 2], wxz1 = Wih0[(256 + nm0) * 2 + 1];
  const float wxn0 = Wih0[(512 + nm0) * 2], wxn1 = Wih0[(512 + nm0) * 2 + 1];
  const float br0  = bih0[nm0] + bhh0[nm0];
  const float bz0  = bih0[256 + nm0] + bhh0[256 + nm0];
  const float bni0 = bih0[512 + nm0], bnh0 = bhh0[512 + nm0];
  const float br1  = bih1[nm0] + bhh1[nm0];
  const float bz1  = bih1[256 + nm0] + bhh1[256 + nm0];
  const float bni1 = bih1[512 + nm0], bnh1 = bhh1[512 + nm0];
  const float fcb  = fc_b[nm0];
  const float owv  = out_W[s * HH + nm0];

  __shared__ float          hf[8 * 260] __attribute__((aligned(16)));
  __shared__ unsigned short hb[8 * 264] __attribute__((aligned(16)));
  __shared__ unsigned short hnb[8 * 264] __attribute__((aligned(16)));
  __shared__ float          es_s[8 * 264] __attribute__((aligned(16)));
  __shared__ unsigned short cacb[8 * 264] __attribute__((aligned(16)));
  __shared__ float          lp[TT * 4 * 2 * 2];       // exp(logit) [j][b][l][o]
  __shared__ float          vw_s[512];                // v_W SWZ'd
  __shared__ float          cpart[2 * 2 * 4 * 256] __attribute__((aligned(16)));  // [jpar][o][b][h]
  __shared__ float          pw_s[64];                 // [wave][b]
  __shared__ float          sinv_s[8];
  __shared__ float          xv_s[BW * TT * 2];        // received cached [b][t][2]
  __shared__ unsigned short wbuf[2][CH48] __attribute__((aligned(16)));  // 2x48KB ring

  for (int x = tid; x < 8 * 260; x += NTHR) hf[x] = 0.0f;
  for (int x = tid; x < 8 * 264; x += NTHR) hb[x] = 0;
  if (tid < 512) { const int o = tid >> 8, g = tid & 255; vw_s[o * 256 + SWZ(g)] = v_W[tid]; }
  if (tid < BW * TT * 2) {
    const int b = tid >> 7, r = tid & 127;
    xv_s[tid] = received[(size_t)(b0 + b) * TT * 2 + r];
  }
  __syncthreads();

  // prologue: stage G1 chunks 0,1 for step 0
  stage48(SR + 0 * CH48, wbuf[0], wave, lane);
  stage48(SR + 1 * CH48, wbuf[1], wave, lane);

#pragma unroll 1
  for (int i = 0; i < TT; ++i) {
    // ===== G1: W1 chunks 0-7 =====
    f4 aR = {0,0,0,0}, aZ = {0,0,0,0}, aN = {0,0,0,0};
#pragma unroll
    for (int c = 0; c < 8; ++c) {
      wait_vm(3);
      __builtin_amdgcn_s_barrier();
      __builtin_amdgcn_sched_barrier(0);
      const unsigned short* wb = wbuf[c & 1];
      const bfrag av = (col < BW) ? *(const bfrag*)&hb[col * 264 + c * 32 + q * 8] : zero_frag();
      const bfrag f0 = *(const bfrag*)&wb[(wave * 3 + 0) * 512 + lane * 8];
      const bfrag f1 = *(const bfrag*)&wb[(wave * 3 + 1) * 512 + lane * 8];
      const bfrag f2 = *(const bfrag*)&wb[(wave * 3 + 2) * 512 + lane * 8];
      aR = mfma16(av, f0, aR); aZ = mfma16(av, f1, aZ); aN = mfma16(av, f2, aN);
      lds_release_bar();
      stage48(SR + (c + 2) * CH48, wbuf[c & 1], wave, lane);   // chunks 2..9
    }
    // G1 epilogue (chunks 8,9 remain in flight; boundary data is LDS-only + buf)
    if (lane < 16) {
#pragma unroll
      for (int reg = 0; reg < 4; reg++) {
        const int b = reg;
        const float xr = xv_s[(b * TT + i) * 2 + 0];
        const float xi = xv_s[(b * TT + i) * 2 + 1];
        const float rr = sigf(xr * wxr0 + xi * wxr1 + br0 + aR[reg]);
        const float zz = sigf(xr * wxz0 + xi * wxz1 + bz0 + aZ[reg]);
        const float nn = tanh_fast(xr * wxn0 + xi * wxn1 + bni0 + rr * (aN[reg] + bnh0));
        const float hn0 = (1.0f - zz) * nn + zz * hf[b * 260 + nm0];
        const unsigned short hv = f2bf(hn0);
        hnb[b * 264 + nm0] = hv;
        buf[((size_t)(b0 + b) * (TT * 2) + i * 2 + 0) * HH + nm0] = hv;   // 4 stores/wave
      }
    }
    lds_release_bar();

    // ===== G2I: W2I chunks 8-15 =====
    f4 iR = {0,0,0,0}, iZ = {0,0,0,0}, iN = {0,0,0,0};
#pragma unroll
    for (int c = 8; c < 16; ++c) {
      wait_vm(c < 10 ? 7 : 3);   // +4 buf stores in queue for c=8,9
      __builtin_amdgcn_s_barrier();
      __builtin_amdgcn_sched_barrier(0);
      const unsigned short* wb = wbuf[c & 1];
      const bfrag av = (col < BW) ? *(const bfrag*)&hnb[col * 264 + (c - 8) * 32 + q * 8] : zero_frag();
      const bfrag f0 = *(const bfrag*)&wb[(wave * 3 + 0) * 512 + lane * 8];
      const bfrag f1 = *(const bfrag*)&wb[(wave * 3 + 1) * 512 + lane * 8];
      const bfrag f2 = *(const bfrag*)&wb[(wave * 3 + 2) * 512 + lane * 8];
      iR = mfma16(av, f0, iR); iZ = mfma16(av, f1, iZ); iN = mfma16(av, f2, iN);
      lds_release_bar();
      stage48(SR + (c + 2) * CH48, wbuf[c & 1], wave, lane);   // chunks 10..17
    }

    // ===== G2H: W2H chunks 16-23 =====
    f4 hR = {0,0,0,0}, hZ = {0,0,0,0}, hN = {0,0,0,0};
#pragma unroll
    for (int c = 16; c < 24; ++c) {
      wait_vm(c < 23 ? 3 : 0);
      __builtin_amdgcn_s_barrier();
      __builtin_amdgcn_sched_barrier(0);
      const unsigned short* wb = wbuf[c & 1];
      const bfrag av = (col < BW) ? *(const bfrag*)&hb[(4 + col) * 264 + (c - 16) * 32 + q * 8] : zero_frag();
      const bfrag f0 = *(const bfrag*)&wb[(wave * 3 + 0) * 512 + lane * 8];
      const bfrag f1 = *(const bfrag*)&wb[(wave * 3 + 1) * 512 + lane * 8];
      const bfrag f2 = *(const bfrag*)&wb[(wave * 3 + 2) * 512 + lane * 8];
      hR = mfma16(av, f0, hR); hZ = mfma16(av, f1, hZ); hN = mfma16(av, f2, hN);
      lds_release_bar();
      if (c + 2 < 24) stage48(SR + (c + 2) * CH48, wbuf[c & 1], wave, lane);   // 18..23
    }
    // prestage B3 chunks 0,1 (both wbuf halves free after loop's last release)
    stage32(B3 + 0 * CH32, wbuf[0], wave, lane);
    stage32(B3 + 1 * CH32, wbuf[1], wave, lane);
    // G2 epilogue
    {
      float pv[4] = {0.f, 0.f, 0.f, 0.f};
      if (lane < 16) {
#pragma unroll
        for (int reg = 0; reg < 4; reg++) {
          const int b = reg;
          const float rr = sigf(iR[reg] + hR[reg] + br1);
          const float zz = sigf(iZ[reg] + hZ[reg] + bz1);
          const float nn = tanh_fast(iN[reg] + bni1 + rr * (hN[reg] + bnh1));
          const float hn1 = (1.0f - zz) * nn + zz * hf[(4 + b) * 260 + nm0];
          const unsigned short hv = f2bf(hn1);
          hnb[(4 + b) * 264 + nm0] = hv;
          buf[((size_t)(b0 + b) * (TT * 2) + i * 2 + 1) * HH + nm0] = hv;   // 4 stores/wave
          pv[reg] += hn1 * owv;
        }
      }
#pragma unroll
      for (int reg = 0; reg < 4; reg++) {
#pragma unroll
        for (int d = 1; d < 16; d <<= 1) pv[reg] += __shfl_xor(pv[reg], d, 64);
      }
      if (lane == 0) {
#pragma unroll
        for (int reg = 0; reg < 4; reg++) pw_s[wave * 4 + reg] = pv[reg];
      }
    }
    lds_release_bar();

    // ===== G3: B3 chunks 0-7 =====
    {
      f4 ac0 = {0,0,0,0}, ac1 = {0,0,0,0};
#pragma unroll
      for (int c = 0; c < 8; ++c) {
        wait_vm(c < 2 ? 6 : (c < 7 ? 2 : 0));   // +4 buf stores in queue for c=0,1
        __builtin_amdgcn_s_barrier();
        __builtin_amdgcn_sched_barrier(0);
        const unsigned short* wb = wbuf[c & 1];
        const bfrag av = (col < 8) ? *(const bfrag*)&hnb[col * 264 + c * 32 + q * 8] : zero_frag();
        const bfrag f0 = *(const bfrag*)&wb[(2 * wave + 0) * 512 + lane * 8];
        const bfrag f1 = *(const bfrag*)&wb[(2 * wave + 1) * 512 + lane * 8];
        ac0 = mfma16(av, f0, ac0);
        ac1 = mfma16(av, f1, ac1);
        lds_release_bar();
        if (c + 2 < 8) stage32(B3 + (c + 2) * CH32, wbuf[c & 1], wave, lane);
      }
      // epilogue
#pragma unroll
      for (int tt = 0; tt < 2; tt++) {
        const f4 acc = tt ? ac1 : ac0;
        const int t = wave * 2 + tt;
        if (lane < 32) {
          const int n = t * 16 + col;
#pragma unroll
          for (int reg = 0; reg < 4; reg++) {
            const int m = q * 4 + reg;   // 0..7 = l*4+b
            const int l = m >> 2, b = m & 3;
            if (t < 16) es_s[(b * 2 + l) * 264 + SWZ(n)] = acc[reg];
            else ehb[((size_t)(b0 + b) * (TT * 2) + i * 2 + l) * HH + (n - 256)] = f2bf(acc[reg]);
          }
        }
      }
      if (tid < 4) {
        float ss = 0.0f;
#pragma unroll
        for (int w = 0; w < 16; w++) ss += pw_s[w * 4 + tid];
        pp[(size_t)(b0 + tid) * TT + i] = ss;
      }
    }
    __syncthreads();   // full drain: energy reads ehb (global RAW)

    // ===== energy: exp(sum_g v*tanh(es+eh)) with 2-stage load pipeline =====
    {
      const int nslot = 64 * (i + 1);
      int slot = tid;
      uv4 cur[4];
      if (slot < nslot) {
        const uv4* ep = (const uv4*)(ehb + ((size_t)(b0 + ((slot >> 3) & 3)) * (TT * 2) +
                                            (slot >> 6) * 2 + ((slot >> 5) & 1)) * HH + (slot & 7) * 32);
#pragma unroll
        for (int u = 0; u < 4; u++) cur[u] = __builtin_nontemporal_load(ep + u);
      }
      for (; slot < nslot; slot += NTHR) {
        const int snext = slot + NTHR;
        uv4 nxt[4];
        if (snext < nslot) {
          const uv4* ep2 = (const uv4*)(ehb + ((size_t)(b0 + ((snext >> 3) & 3)) * (TT * 2) +
                                               (snext >> 6) * 2 + ((snext >> 5) & 1)) * HH + (snext & 7) * 32);
#pragma unroll
          for (int u = 0; u < 4; u++) nxt[u] = __builtin_nontemporal_load(ep2 + u);
        } else {
#pragma unroll
          for (int u = 0; u < 4; u++) nxt[u] = cur[u];
        }
        const int g8 = slot & 7;
        const int b  = (slot >> 3) & 3;
        const int l  = (slot >> 5) & 1;
        const int j  = slot >> 6;
        const int eb = (b * 2 + l) * 264;
        float l0 = 0.0f, l1 = 0.0f;
#pragma unroll
        for (int u = 0; u < 4; u++) {
#pragma unroll
          for (int k = 0; k < 4; k++) {
            const int m = u * 8 + k * 2;
            const float e0 = tanh_fast(es_s[eb + (m * 8 + g8)] + bf_lo(cur[u][k]));
            const float e1 = tanh_fast(es_s[eb + ((m + 1) * 8 + g8)] + bf_hi(cur[u][k]));
            l0 = fmaf(e0, vw_s[m * 8 + g8], fmaf(e1, vw_s[(m + 1) * 8 + g8], l0));
            l1 = fmaf(e0, vw_s[256 + m * 8 + g8], fmaf(e1, vw_s[256 + (m + 1) * 8 + g8], l1));
          }
        }
#pragma unroll
        for (int d = 1; d < 8; d <<= 1) { l0 += __shfl_xor(l0, d, 64); l1 += __shfl_xor(l1, d, 64); }
        if (g8 == 0) {
          lp[((j * 4 + b) * 2 + l) * 2 + 0] = __expf(l0);
          lp[((j * 4 + b) * 2 + l) * 2 + 1] = __expf(l1);
        }
#pragma unroll
        for (int u = 0; u < 4; u++) cur[u] = nxt[u];
      }
    }
    __syncthreads();

    // ===== sinv (waves 0-7) + context (dword loads, 2-way j-split, lookahead) =====
    {
      if (wave < 8) {
        const int b = wave >> 1, o = wave & 1;
        const int jl2 = 2 * (i + 1);
        const int jl0 = lane, jl1 = lane + 64;
        float sa = 0.0f;
        if (jl0 < jl2) sa += lp[((jl0 >> 1) * 4 + b) * 4 + (jl0 & 1) * 2 + o];
        if (jl1 < jl2) sa += lp[((jl1 >> 1) * 4 + b) * 4 + (jl1 & 1) * 2 + o];
#pragma unroll
        for (int d = 1; d < 64; d <<= 1) sa += __shfl_xor(sa, d, 64);
        if (lane == 0) sinv_s[b * 2 + o] = rcpf(sa);
      }
      const int h2   = tid & 127;          // dword slice (2 h-values)
      const int jpar = (tid >> 7) & 1;     // j mod 2
      const int cb   = tid >> 8;           // batch 0..3
      const unsigned int* bp = (const unsigned int*)(buf + ((size_t)(b0 + cb) * (TT * 2)) * HH);
      float c00 = 0.f, c01 = 0.f, c10 = 0.f, c11 = 0.f;
      unsigned int aj0 = 0, aj1 = 0, bj0 = 0, bj1 = 0;
      int j = jpar;
      if (j <= i) {
        aj0 = __builtin_nontemporal_load(bp + (j * 2 + 0) * 128 + h2);
        aj1 = __builtin_nontemporal_load(bp + (j * 2 + 1) * 128 + h2);
        // prefetch j+2 (address stays inside workspace even past i)
        bj0 = __builtin_nontemporal_load(bp + ((j + 2) * 2 + 0) * 128 + h2);
        bj1 = __builtin_nontemporal_load(bp + ((j + 2) * 2 + 1) * 128 + h2);
      }
      for (; j <= i; j += 2) {
        unsigned int cj0 = 0, cj1 = 0;
        if (j + 4 <= i) {
          cj0 = __builtin_nontemporal_load(bp + ((j + 4) * 2 + 0) * 128 + h2);
          cj1 = __builtin_nontemporal_load(bp + ((j + 4) * 2 + 1) * 128 + h2);
        }
#pragma unroll
        for (int l = 0; l < 2; l++) {
          const unsigned int u = l ? aj1 : aj0;
          const float e0 = lp[((j * 4 + cb) * 2 + l) * 2 + 0];
          const float e1 = lp[((j * 4 + cb) * 2 + l) * 2 + 1];
          const float v0 = bf_lo(u), v1 = bf_hi(u);
          c00 = fmaf(e0, v0, c00); c01 = fmaf(e0, v1, c01);
          c10 = fmaf(e1, v0, c10); c11 = fmaf(e1, v1, c11);
        }
        aj0 = bj0; aj1 = bj1; bj0 = cj0; bj1 = cj1;
      }
      ((float2*)&cpart[((jpar * 2 + 0) * 4 + cb) * 256])[h2] = make_float2(c00, c01);
      ((float2*)&cpart[((jpar * 2 + 1) * 4 + cb) * 256])[h2] = make_float2(c10, c11);
    }
    __syncthreads();

    // ===== prestage B4 chunks 0,1; fold context halves -> cacb bf16 =====
    stage32(B4 + 0 * CH32, wbuf[0], wave, lane);
    stage32(B4 + 1 * CH32, wbuf[1], wave, lane);
    for (int x = tid; x < 2 * BW * HH; x += NTHR) {
      const int g = x & 255, b = (x >> 8) & 3, o = x >> 10;
      const float v = (cpart[((0 * 2 + o) * 4 + b) * 256 + g] +
                       cpart[((1 * 2 + o) * 4 + b) * 256 + g]) *
                      sinv_s[b * 2 + o];
      cacb[(o * 4 + b) * 264 + g] = f2bf(v);
    }
    __syncthreads();   // drains B4 0,1 (partial hide under fold)

    // ===== G4: B4 chunks 0-7 -> new carry =====
    {
      f4 acc = {0, 0, 0, 0};
#pragma unroll
      for (int cc = 0; cc < 8; ++cc) {
        wait_vm(cc < 7 ? 2 : 0);
        __builtin_amdgcn_s_barrier();
        __builtin_amdgcn_sched_barrier(0);
        const unsigned short* wb = wbuf[cc & 1];
        bfrag a0v, a1v;
        if (col < 8) {
          a0v = (cc < 4) ? *(const bfrag*)&cacb[col * 264 + cc * 64 + q * 8]
                         : *(const bfrag*)&hnb[col * 264 + (cc - 4) * 64 + q * 8];
          a1v = (cc < 4) ? *(const bfrag*)&cacb[col * 264 + cc * 64 + 32 + q * 8]
                         : *(const bfrag*)&hnb[col * 264 + (cc - 4) * 64 + 32 + q * 8];
        } else { a0v = zero_frag(); a1v = zero_frag(); }
        const bfrag g0 = *(const bfrag*)&wb[(wave * 2 + 0) * 512 + lane * 8];
        const bfrag g1 = *(const bfrag*)&wb[(wave * 2 + 1) * 512 + lane * 8];
        acc = mfma16(a0v, g0, acc);
        acc = mfma16(a1v, g1, acc);
        lds_release_bar();
        if (cc + 2 < 8) stage32(B4 + (cc + 2) * CH32, wbuf[cc & 1], wave, lane);
      }
      // prestage next step's G1 chunks 0,1 (kept in flight across step boundary)
      if (i + 1 < TT) {
        stage48(SR + 0 * CH48, wbuf[0], wave, lane);
        stage48(SR + 1 * CH48, wbuf[1], wave, lane);
      }
      if (lane < 32) {
#pragma unroll
        for (int reg = 0; reg < 4; reg++) {
          const int m = q * 4 + reg;   // 0..7 = o*4+b
          const float v = acc[reg] + fcb;
          hf[m * 260 + nm0] = v;
          hb[m * 264 + nm0] = f2bf(v);
        }
      }
    }
    lds_release_bar();   // LDS-only boundary (hf/hb); keeps G1 prefetch in flight
  }
}

__global__ __launch_bounds__(256) void final_combine(const float* __restrict__ ws_p,
                                                     const float* __restrict__ out_b,
                                                     float* __restrict__ out) {
  const int gidx = blockIdx.x * blockDim.x + threadIdx.x;
  if (gidx >= BATCH * TT) return;
  const int b = gidx >> 6;
  const int t = gidx & 63;
  const int idx = (t >= TT - DD - 1) ? (TT - 1) : (t + DD);
  const float* p1 = ws_p;
  const float* p2 = ws_p + (size_t)BATCH * TT;
  const float v = p1[(size_t)b * TT + t] + p2[(size_t)b * TT + idx] + out_b[0];
  out[gidx] = 1.0f / (1.0f + __expf(-v));
}

extern "C" void kernel_launch(void* const* d_in, const int* in_sizes, int n_in,
                              void* d_out, int out_size, void* d_ws, size_t ws_size,
                              hipStream_t stream) {
  const float* received = (const float*)d_in[0];
  const float* g1_Wih0 = (const float*)d_in[1];
  const float* g1_Whh0 = (const float*)d_in[2];
  const float* g1_bih0 = (const float*)d_in[3];
  const float* g1_bhh0 = (const float*)d_in[4];
  const float* g1_Wih1 = (const float*)d_in[5];
  const float* g1_Whh1 = (const float*)d_in[6];
  const float* g1_bih1 = (const float*)d_in[7];
  const float* g1_bhh1 = (const float*)d_in[8];
  const float* g2_Wih0 = (const float*)d_in[9];
  const float* g2_Whh0 = (const float*)d_in[10];
  const float* g2_bih0 = (const float*)d_in[11];
  const float* g2_bhh0 = (const float*)d_in[12];
  const float* g2_Wih1 = (const float*)d_in[13];
  const float* g2_Whh1 = (const float*)d_in[14];
  const float* g2_bih1 = (const float*)d_in[15];
  const float* g2_bhh1 = (const float*)d_in[16];
  const float* fc_W   = (const float*)d_in[17];
  const float* fc_b   = (const float*)d_in[18];
  const float* attn_W = (const float*)d_in[19];
  const float* v_W    = (const float*)d_in[20];
  const float* out_W  = (const float*)d_in[21];
  const float* out_b  = (const float*)d_in[22];

  // ws layout: fp32 pp[2*B*T] | bf16 buf[2*B*T*2*H] | bf16 ehb[same] | bf16 wf[WF_TOTAL]
  float* ws_p = (float*)d_ws;
  unsigned short* buf = (unsigned short*)(ws_p + 2 * BATCH * TT);
  unsigned short* ehb = buf + (size_t)2 * BATCH * TT * 2 * HH;
  unsigned short* wf  = ehb + (size_t)2 * BATCH * TT * 2 * HH;

  hipLaunchKernelGGL(prep_weights, dim3((WF_TOTAL + 255) / 256), dim3(256), 0, stream,
                     g1_Whh0, g1_Wih1, g1_Whh1, g2_Whh0, g2_Wih1, g2_Whh1,
                     attn_W, fc_W, wf);

  hipLaunchKernelGGL(gru_attn, dim3(NBLK), dim3(NTHR), 0, stream,
                     received,
                     g1_Wih0, g1_bih0, g1_bhh0, g1_bih1, g1_bhh1,
                     g2_Wih0, g2_bih0, g2_bhh0, g2_bih1, g2_bhh1,
                     fc_b, v_W, out_W, wf, buf, ehb, ws_p);

  hipLaunchKernelGGL(final_combine, dim3((BATCH * TT + 255) / 256), dim3(256), 0, stream,
                     ws_p, out_b, (float*)d_out);
}

// Round 9
// 5713.484 us; speedup vs baseline: 1.0839x; 1.0839x over previous
//
#include <hip/hip_runtime.h>

// Problem constants
#define BATCH 256
#define TT    64
#define HH    256
#define DD    8

// Tiling: 2 stacks * 64 batch-blocks of BW=4 -> 128 WGs, 1024 thr (16 waves)
// Round 9: round-8 chunk streaming WITHOUT intra-phase lockstep barriers.
// The LDS weight ring is wave-private (wave w stages and consumes only its
// own region), so per-chunk WG barriers were pure serialization: each gate
// waited on the slowest wave's loads with only ~2 chunks of lookahead vs
// ~2000cy congested latency. Now each wave free-runs stage->vmcnt->consume;
// WG syncs only at true cross-wave boundaries (7/step). Geometry-change
// (48KB<->32KB region) prestages sit strictly after boundary barriers.
#define BW    4
#define NTHR  1024
#define NBLK  (2 * (BATCH / BW))

#define CH48  24576   // elems per 48KB chunk (W1/W2I/W2H)
#define CH32  16384   // elems per 32KB chunk (B3/B4)

typedef __attribute__((ext_vector_type(8))) short bfrag;   // 8 bf16 (MFMA A/B operand)
typedef __attribute__((ext_vector_type(4))) float f4;      // MFMA C/D
typedef __attribute__((ext_vector_type(4))) unsigned int uv4;

#define SWZ(g) ((((g) & 31) << 3) | ((g) >> 5))

__device__ __forceinline__ float rcpf(float x) { return __builtin_amdgcn_rcpf(x); }
__device__ __forceinline__ float sigf(float x) { return rcpf(1.0f + __expf(-x)); }
__device__ __forceinline__ float tanh_fast(float x) {
  const float e = __expf(-2.0f * x);
  return __builtin_fmaf(2.0f, rcpf(1.0f + e), -1.0f);
}
__device__ __forceinline__ unsigned short f2bf(float f) {
  union { float f; unsigned int u; } v; v.f = f;
  return (unsigned short)((v.u + 0x7fffu + ((v.u >> 16) & 1u)) >> 16);
}
__device__ __forceinline__ float bf_lo(unsigned int u) {
  union { unsigned int u; float f; } v; v.u = u << 16; return v.f;
}
__device__ __forceinline__ float bf_hi(unsigned int u) {
  union { unsigned int u; float f; } v; v.u = u & 0xffff0000u; return v.f;
}
__device__ __forceinline__ bfrag zero_frag() {
  bfrag r;
#pragma unroll
  for (int x = 0; x < 8; x++) r[x] = 0;
  return r;
}
__device__ __forceinline__ f4 mfma16(bfrag a, bfrag b, f4 c) {
  return __builtin_amdgcn_mfma_f32_16x16x32_bf16(a, b, c, 0, 0, 0);
}

// per-wave counted vmem wait (chunk pipeline fence; no WG sync)
__device__ __forceinline__ void wait_vm(int n) {
  if (n == 0)      asm volatile("s_waitcnt vmcnt(0)" ::: "memory");
  else if (n == 2) asm volatile("s_waitcnt vmcnt(2)" ::: "memory");
  else if (n == 3) asm volatile("s_waitcnt vmcnt(3)" ::: "memory");
  else             asm volatile("s_waitcnt vmcnt(7)" ::: "memory");
  __builtin_amdgcn_sched_barrier(0);
}
// cross-wave LDS boundary: ds ops retired + barrier (vmem prefetch survives)
__device__ __forceinline__ void lds_release_bar() {
  asm volatile("s_waitcnt lgkmcnt(0)" ::: "memory");
  __builtin_amdgcn_sched_barrier(0);
  __builtin_amdgcn_s_barrier();
  __builtin_amdgcn_sched_barrier(0);
}

// ---- async global->LDS staging (16B per lane; LDS dest = uniform base + lane*16)
__device__ __forceinline__ void gl_lds16(const unsigned short* g, unsigned short* l) {
  __builtin_amdgcn_global_load_lds(
      (const __attribute__((address_space(1))) unsigned int*)g,
      (__attribute__((address_space(3))) unsigned int*)l, 16, 0, 0);
}
// 48KB chunk: 3 loads/wave (3KB/wave region, self-staged self-consumed)
__device__ __forceinline__ void stage48(const unsigned short* g, unsigned short* l,
                                        int wave, int lane) {
#pragma unroll
  for (int r = 0; r < 3; ++r)
    gl_lds16(g + wave * 1536 + r * 512 + lane * 8, l + wave * 1536 + r * 512);
}
// 32KB chunk: 2 loads/wave (2KB/wave region)
__device__ __forceinline__ void stage32(const unsigned short* g, unsigned short* l,
                                        int wave, int lane) {
#pragma unroll
  for (int r = 0; r < 2; ++r)
    gl_lds16(g + wave * 1024 + r * 512 + lane * 8, l + wave * 1024 + r * 512);
}

// ---------- weight fragment layout (chunk-major, as round 8) ----------
#define W1_ELEMS  196608
#define STACK_W   (3 * W1_ELEMS)
#define B3_OFF    (2 * STACK_W)
#define B4_OFF    (B3_OFF + 131072)
#define WF_TOTAL  (B4_OFF + 131072)

__global__ __launch_bounds__(256) void prep_weights(
    const float* __restrict__ g1_Whh0, const float* __restrict__ g1_Wih1, const float* __restrict__ g1_Whh1,
    const float* __restrict__ g2_Whh0, const float* __restrict__ g2_Wih1, const float* __restrict__ g2_Whh1,
    const float* __restrict__ attn_W, const float* __restrict__ fc_W,
    unsigned short* __restrict__ wf) {
  const int id = blockIdx.x * 256 + threadIdx.x;
  if (id >= WF_TOTAL) return;
  float src;
  if (id < 2 * STACK_W) {
    const int s = id / STACK_W, r = id % STACK_W;
    const int mm = r / W1_ELEMS, e = r % W1_ELEMS;
    const int c = e / CH48, e2 = e % CH48;
    const int wg = e2 >> 9, l8 = e2 & 511;
    const int w = wg / 3, g = wg % 3;
    const int lane = l8 >> 3, j = l8 & 7;
    const int n = w * 16 + (lane & 15);
    const int k = c * 32 + ((lane >> 4) << 3) + j;
    const float* W = (mm == 0) ? (s ? g2_Whh0 : g1_Whh0)
                   : (mm == 1) ? (s ? g2_Wih1 : g1_Wih1)
                               : (s ? g2_Whh1 : g1_Whh1);
    src = W[(g * 256 + n) * 256 + k];
  } else if (id < B4_OFF) {
    const int e = id - B3_OFF;
    const int c = e / CH32, e2 = e % CH32;
    const int t = e2 >> 9, l8 = e2 & 511;
    const int lane = l8 >> 3, j = l8 & 7;
    const int n = t * 16 + (lane & 15);
    const int k = c * 32 + ((lane >> 4) << 3) + j;
    src = (n < 256) ? attn_W[n * 512 + k] : attn_W[(n - 256) * 512 + 256 + k];
  } else {
    const int e = id - B4_OFF;
    const int cc = e / CH32, e2 = e % CH32;
    const int w = e2 >> 10, c2 = (e2 >> 9) & 1, l8 = e2 & 511;
    const int lane = l8 >> 3, j = l8 & 7;
    const int c = cc * 2 + c2;
    const int n = w * 16 + (lane & 15);
    const int k = c * 32 + ((lane >> 4) << 3) + j;
    src = fc_W[n * 512 + k];
  }
  wf[id] = f2bf(src);
}

__global__ __launch_bounds__(NTHR) void gru_attn(
    const float* __restrict__ received,
    const float* __restrict__ g1_Wih0, const float* __restrict__ g1_bih0, const float* __restrict__ g1_bhh0,
    const float* __restrict__ g1_bih1, const float* __restrict__ g1_bhh1,
    const float* __restrict__ g2_Wih0, const float* __restrict__ g2_bih0, const float* __restrict__ g2_bhh0,
    const float* __restrict__ g2_bih1, const float* __restrict__ g2_bhh1,
    const float* __restrict__ fc_b, const float* __restrict__ v_W, const float* __restrict__ out_W,
    const unsigned short* __restrict__ wf,
    unsigned short* __restrict__ buf_g, unsigned short* __restrict__ ehb_g,
    float* __restrict__ ws_p) {
  const int tid  = threadIdx.x;
  const int lane = tid & 63, wave = tid >> 6;      // 16 waves
  const int col  = lane & 15, q = lane >> 4;
  const int s    = blockIdx.x & 1;                 // stack parity -> XCD parity
  const int b0   = (blockIdx.x >> 1) * BW;

  const float* Wih0 = s ? g2_Wih0 : g1_Wih0;
  const float* bih0 = s ? g2_bih0 : g1_bih0;
  const float* bhh0 = s ? g2_bhh0 : g1_bhh0;
  const float* bih1 = s ? g2_bih1 : g1_bih1;
  const float* bhh1 = s ? g2_bhh1 : g1_bhh1;

  const unsigned short* SR = wf + (size_t)s * STACK_W;   // 24 CH48 chunks
  const unsigned short* B3 = wf + B3_OFF;                // 8 CH32 chunks
  const unsigned short* B4 = wf + B4_OFF;                // 8 CH32 chunks

  unsigned short* buf = buf_g + (size_t)s * BATCH * TT * 2 * HH;
  unsigned short* ehb = ehb_g + (size_t)s * BATCH * TT * 2 * HH;
  float* pp = ws_p + (size_t)s * BATCH * TT;

  // Per-lane persistent constants: each wave owns ONE 16-output group nm = wave*16+col
  const int nm0 = wave * 16 + col;
  const float wxr0 = Wih0[nm0 * 2],         wxr1 = Wih0[nm0 * 2 + 1];
  const float wxz0 = Wih0[(256 + nm0) * 2], wxz1 = Wih0[(256 + nm0) * 2 + 1];
  const float wxn0 = Wih0[(512 + nm0) * 2], wxn1 = Wih0[(512 + nm0) * 2 + 1];
  const float br0  = bih0[nm0] + bhh0[nm0];
  const float bz0  = bih0[256 + nm0] + bhh0[256 + nm0];
  const float bni0 = bih0[512 + nm0], bnh0 = bhh0[512 + nm0];
  const float br1  = bih1[nm0] + bhh1[nm0];
  const float bz1  = bih1[256 + nm0] + bhh1[256 + nm0];
  const float bni1 = bih1[512 + nm0], bnh1 = bhh1[512 + nm0];
  const float fcb  = fc_b[nm0];
  const float owv  = out_W[s * HH + nm0];

  __shared__ float          hf[8 * 260] __attribute__((aligned(16)));
  __shared__ unsigned short hb[8 * 264] __attribute__((aligned(16)));
  __shared__ unsigned short hnb[8 * 264] __attribute__((aligned(16)));
  __shared__ float          es_s[8 * 264] __attribute__((aligned(16)));
  __shared__ unsigned short cacb[8 * 264] __attribute__((aligned(16)));
  __shared__ float          lp[TT * 4 * 2 * 2];       // exp(logit) [j][b][l][o]
  __shared__ float          vw_s[512];                // v_W SWZ'd
  __shared__ float          cpart[2 * 2 * 4 * 256] __attribute__((aligned(16)));  // [jpar][o][b][h]
  __shared__ float          pw_s[64];                 // [wave][b]
  __shared__ float          sinv_s[8];
  __shared__ float          xv_s[BW * TT * 2];        // received cached [b][t][2]
  __shared__ unsigned short wbuf[2][CH48] __attribute__((aligned(16)));  // 2x48KB ring

  for (int x = tid; x < 8 * 260; x += NTHR) hf[x] = 0.0f;
  for (int x = tid; x < 8 * 264; x += NTHR) hb[x] = 0;
  if (tid < 512) { const int o = tid >> 8, g = tid & 255; vw_s[o * 256 + SWZ(g)] = v_W[tid]; }
  if (tid < BW * TT * 2) {
    const int b = tid >> 7, r = tid & 127;
    xv_s[tid] = received[(size_t)(b0 + b) * TT * 2 + r];
  }
  __syncthreads();

  // prologue: stage G1 chunks 0,1 for step 0
  stage48(SR + 0 * CH48, wbuf[0], wave, lane);
  stage48(SR + 1 * CH48, wbuf[1], wave, lane);

#pragma unroll 1
  for (int i = 0; i < TT; ++i) {
    // ===== G1: W1 chunks 0-7 (free-running per-wave pipeline) =====
    f4 aR = {0,0,0,0}, aZ = {0,0,0,0}, aN = {0,0,0,0};
#pragma unroll
    for (int c = 0; c < 8; ++c) {
      wait_vm(3);
      const unsigned short* wb = wbuf[c & 1];
      const bfrag av = (col < BW) ? *(const bfrag*)&hb[col * 264 + c * 32 + q * 8] : zero_frag();
      const bfrag f0 = *(const bfrag*)&wb[(wave * 3 + 0) * 512 + lane * 8];
      const bfrag f1 = *(const bfrag*)&wb[(wave * 3 + 1) * 512 + lane * 8];
      const bfrag f2 = *(const bfrag*)&wb[(wave * 3 + 2) * 512 + lane * 8];
      aR = mfma16(av, f0, aR); aZ = mfma16(av, f1, aZ); aN = mfma16(av, f2, aN);
      __builtin_amdgcn_sched_barrier(0);
      stage48(SR + (c + 2) * CH48, wbuf[c & 1], wave, lane);   // chunks 2..9
    }
    // G1 epilogue
    if (lane < 16) {
#pragma unroll
      for (int reg = 0; reg < 4; reg++) {
        const int b = reg;
        const float xr = xv_s[(b * TT + i) * 2 + 0];
        const float xi = xv_s[(b * TT + i) * 2 + 1];
        const float rr = sigf(xr * wxr0 + xi * wxr1 + br0 + aR[reg]);
        const float zz = sigf(xr * wxz0 + xi * wxz1 + bz0 + aZ[reg]);
        const float nn = tanh_fast(xr * wxn0 + xi * wxn1 + bni0 + rr * (aN[reg] + bnh0));
        const float hn0 = (1.0f - zz) * nn + zz * hf[b * 260 + nm0];
        const unsigned short hv = f2bf(hn0);
        hnb[b * 264 + nm0] = hv;
        buf[((size_t)(b0 + b) * (TT * 2) + i * 2 + 0) * HH + nm0] = hv;   // 4 stores/wave
      }
    }
    lds_release_bar();   // hnb ready; chunk 8,9 prefetch stays in flight

    // ===== G2I: W2I chunks 8-15 =====
    f4 iR = {0,0,0,0}, iZ = {0,0,0,0}, iN = {0,0,0,0};
#pragma unroll
    for (int c = 8; c < 16; ++c) {
      wait_vm(c < 10 ? 7 : 3);   // +4 buf stores in queue for c=8,9
      const unsigned short* wb = wbuf[c & 1];
      const bfrag av = (col < BW) ? *(const bfrag*)&hnb[col * 264 + (c - 8) * 32 + q * 8] : zero_frag();
      const bfrag f0 = *(const bfrag*)&wb[(wave * 3 + 0) * 512 + lane * 8];
      const bfrag f1 = *(const bfrag*)&wb[(wave * 3 + 1) * 512 + lane * 8];
      const bfrag f2 = *(const bfrag*)&wb[(wave * 3 + 2) * 512 + lane * 8];
      iR = mfma16(av, f0, iR); iZ = mfma16(av, f1, iZ); iN = mfma16(av, f2, iN);
      __builtin_amdgcn_sched_barrier(0);
      stage48(SR + (c + 2) * CH48, wbuf[c & 1], wave, lane);   // chunks 10..17
    }

    // ===== G2H: W2H chunks 16-23 (no boundary needed: reads stable hb) =====
    f4 hR = {0,0,0,0}, hZ = {0,0,0,0}, hN = {0,0,0,0};
#pragma unroll
    for (int c = 16; c < 24; ++c) {
      wait_vm(c < 23 ? 3 : 0);
      const unsigned short* wb = wbuf[c & 1];
      const bfrag av = (col < BW) ? *(const bfrag*)&hb[(4 + col) * 264 + (c - 16) * 32 + q * 8] : zero_frag();
      const bfrag f0 = *(const bfrag*)&wb[(wave * 3 + 0) * 512 + lane * 8];
      const bfrag f1 = *(const bfrag*)&wb[(wave * 3 + 1) * 512 + lane * 8];
      const bfrag f2 = *(const bfrag*)&wb[(wave * 3 + 2) * 512 + lane * 8];
      hR = mfma16(av, f0, hR); hZ = mfma16(av, f1, hZ); hN = mfma16(av, f2, hN);
      __builtin_amdgcn_sched_barrier(0);
      if (c + 2 < 24) stage48(SR + (c + 2) * CH48, wbuf[c & 1], wave, lane);   // 18..23
    }
    // G2 epilogue
    {
      float pv[4] = {0.f, 0.f, 0.f, 0.f};
      if (lane < 16) {
#pragma unroll
        for (int reg = 0; reg < 4; reg++) {
          const int b = reg;
          const float rr = sigf(iR[reg] + hR[reg] + br1);
          const float zz = sigf(iZ[reg] + hZ[reg] + bz1);
          const float nn = tanh_fast(iN[reg] + bni1 + rr * (hN[reg] + bnh1));
          const float hn1 = (1.0f - zz) * nn + zz * hf[(4 + b) * 260 + nm0];
          const unsigned short hv = f2bf(hn1);
          hnb[(4 + b) * 264 + nm0] = hv;
          buf[((size_t)(b0 + b) * (TT * 2) + i * 2 + 1) * HH + nm0] = hv;   // 4 stores/wave
          pv[reg] += hn1 * owv;
        }
      }
#pragma unroll
      for (int reg = 0; reg < 4; reg++) {
#pragma unroll
        for (int d = 1; d < 16; d <<= 1) pv[reg] += __shfl_xor(pv[reg], d, 64);
      }
      if (lane == 0) {
#pragma unroll
        for (int reg = 0; reg < 4; reg++) pw_s[wave * 4 + reg] = pv[reg];
      }
    }
    lds_release_bar();   // hnb layer-1 ready; ALL waves past W2H reads (48->32 geometry change)
    // prestage B3 chunks 0,1 (safe: post-barrier)
    stage32(B3 + 0 * CH32, wbuf[0], wave, lane);
    stage32(B3 + 1 * CH32, wbuf[1], wave, lane);

    // ===== G3: B3 chunks 0-7 =====
    {
      f4 ac0 = {0,0,0,0}, ac1 = {0,0,0,0};
#pragma unroll
      for (int c = 0; c < 8; ++c) {
        wait_vm(c < 7 ? 2 : 0);
        const unsigned short* wb = wbuf[c & 1];
        const bfrag av = (col < 8) ? *(const bfrag*)&hnb[col * 264 + c * 32 + q * 8] : zero_frag();
        const bfrag f0 = *(const bfrag*)&wb[(2 * wave + 0) * 512 + lane * 8];
        const bfrag f1 = *(const bfrag*)&wb[(2 * wave + 1) * 512 + lane * 8];
        ac0 = mfma16(av, f0, ac0);
        ac1 = mfma16(av, f1, ac1);
        __builtin_amdgcn_sched_barrier(0);
        if (c + 2 < 8) stage32(B3 + (c + 2) * CH32, wbuf[c & 1], wave, lane);
      }
      // epilogue
#pragma unroll
      for (int tt = 0; tt < 2; tt++) {
        const f4 acc = tt ? ac1 : ac0;
        const int t = wave * 2 + tt;
        if (lane < 32) {
          const int n = t * 16 + col;
#pragma unroll
          for (int reg = 0; reg < 4; reg++) {
            const int m = q * 4 + reg;   // 0..7 = l*4+b
            const int l = m >> 2, b = m & 3;
            if (t < 16) es_s[(b * 2 + l) * 264 + SWZ(n)] = acc[reg];
            else ehb[((size_t)(b0 + b) * (TT * 2) + i * 2 + l) * HH + (n - 256)] = f2bf(acc[reg]);
          }
        }
      }
      if (tid < 4) {
        float ss = 0.0f;
#pragma unroll
        for (int w = 0; w < 16; w++) ss += pw_s[w * 4 + tid];
        pp[(size_t)(b0 + tid) * TT + i] = ss;
      }
    }
    __syncthreads();   // full drain: energy reads ehb; context reads buf (global RAW)

    // ===== energy: exp(sum_g v*tanh(es+eh)) with 2-stage load pipeline =====
    {
      const int nslot = 64 * (i + 1);
      int slot = tid;
      uv4 cur[4];
      if (slot < nslot) {
        const uv4* ep = (const uv4*)(ehb + ((size_t)(b0 + ((slot >> 3) & 3)) * (TT * 2) +
                                            (slot >> 6) * 2 + ((slot >> 5) & 1)) * HH + (slot & 7) * 32);
#pragma unroll
        for (int u = 0; u < 4; u++) cur[u] = __builtin_nontemporal_load(ep + u);
      }
      for (; slot < nslot; slot += NTHR) {
        const int snext = slot + NTHR;
        uv4 nxt[4];
        if (snext < nslot) {
          const uv4* ep2 = (const uv4*)(ehb + ((size_t)(b0 + ((snext >> 3) & 3)) * (TT * 2) +
                                               (snext >> 6) * 2 + ((snext >> 5) & 1)) * HH + (snext & 7) * 32);
#pragma unroll
          for (int u = 0; u < 4; u++) nxt[u] = __builtin_nontemporal_load(ep2 + u);
        } else {
#pragma unroll
          for (int u = 0; u < 4; u++) nxt[u] = cur[u];
        }
        const int g8 = slot & 7;
        const int b  = (slot >> 3) & 3;
        const int l  = (slot >> 5) & 1;
        const int j  = slot >> 6;
        const int eb = (b * 2 + l) * 264;
        float l0 = 0.0f, l1 = 0.0f;
#pragma unroll
        for (int u = 0; u < 4; u++) {
#pragma unroll
          for (int k = 0; k < 4; k++) {
            const int m = u * 8 + k * 2;
            const float e0 = tanh_fast(es_s[eb + (m * 8 + g8)] + bf_lo(cur[u][k]));
            const float e1 = tanh_fast(es_s[eb + ((m + 1) * 8 + g8)] + bf_hi(cur[u][k]));
            l0 = fmaf(e0, vw_s[m * 8 + g8], fmaf(e1, vw_s[(m + 1) * 8 + g8], l0));
            l1 = fmaf(e0, vw_s[256 + m * 8 + g8], fmaf(e1, vw_s[256 + (m + 1) * 8 + g8], l1));
          }
        }
#pragma unroll
        for (int d = 1; d < 8; d <<= 1) { l0 += __shfl_xor(l0, d, 64); l1 += __shfl_xor(l1, d, 64); }
        if (g8 == 0) {
          lp[((j * 4 + b) * 2 + l) * 2 + 0] = __expf(l0);
          lp[((j * 4 + b) * 2 + l) * 2 + 1] = __expf(l1);
        }
#pragma unroll
        for (int u = 0; u < 4; u++) cur[u] = nxt[u];
      }
    }
    lds_release_bar();   // lp ready (LDS-only boundary)

    // ===== sinv (waves 0-7) + context (dword loads, 2-way j-split, 4-deep lookahead) =====
    {
      if (wave < 8) {
        const int b = wave >> 1, o = wave & 1;
        const int jl2 = 2 * (i + 1);
        const int jl0 = lane, jl1 = lane + 64;
        float sa = 0.0f;
        if (jl0 < jl2) sa += lp[((jl0 >> 1) * 4 + b) * 4 + (jl0 & 1) * 2 + o];
        if (jl1 < jl2) sa += lp[((jl1 >> 1) * 4 + b) * 4 + (jl1 & 1) * 2 + o];
#pragma unroll
        for (int d = 1; d < 64; d <<= 1) sa += __shfl_xor(sa, d, 64);
        if (lane == 0) sinv_s[b * 2 + o] = rcpf(sa);
      }
      const int h2   = tid & 127;          // dword slice (2 h-values)
      const int jpar = (tid >> 7) & 1;     // j mod 2
      const int cb   = tid >> 8;           // batch 0..3
      const unsigned int* bp = (const unsigned int*)(buf + ((size_t)(b0 + cb) * (TT * 2)) * HH);
      float c00 = 0.f, c01 = 0.f, c10 = 0.f, c11 = 0.f;
      unsigned int a0v = 0, a1v = 0, b0v = 0, b1v = 0;
      unsigned int c0v = 0, c1v = 0, d0v = 0, d1v = 0;
      int j = jpar;
      if (j <= i) {
        a0v = __builtin_nontemporal_load(bp + (j * 2 + 0) * 128 + h2);
        a1v = __builtin_nontemporal_load(bp + (j * 2 + 1) * 128 + h2);
        b0v = __builtin_nontemporal_load(bp + ((j + 2) * 2 + 0) * 128 + h2);
        b1v = __builtin_nontemporal_load(bp + ((j + 2) * 2 + 1) * 128 + h2);
        c0v = __builtin_nontemporal_load(bp + ((j + 4) * 2 + 0) * 128 + h2);
        c1v = __builtin_nontemporal_load(bp + ((j + 4) * 2 + 1) * 128 + h2);
        d0v = __builtin_nontemporal_load(bp + ((j + 6) * 2 + 0) * 128 + h2);
        d1v = __builtin_nontemporal_load(bp + ((j + 6) * 2 + 1) * 128 + h2);
      }
      for (; j <= i; j += 2) {
        unsigned int e0v = 0, e1v = 0;
        if (j + 8 <= i) {
          e0v = __builtin_nontemporal_load(bp + ((j + 8) * 2 + 0) * 128 + h2);
          e1v = __builtin_nontemporal_load(bp + ((j + 8) * 2 + 1) * 128 + h2);
        }
#pragma unroll
        for (int l = 0; l < 2; l++) {
          const unsigned int u = l ? a1v : a0v;
          const float e0 = lp[((j * 4 + cb) * 2 + l) * 2 + 0];
          const float e1 = lp[((j * 4 + cb) * 2 + l) * 2 + 1];
          const float v0 = bf_lo(u), v1 = bf_hi(u);
          c00 = fmaf(e0, v0, c00); c01 = fmaf(e0, v1, c01);
          c10 = fmaf(e1, v0, c10); c11 = fmaf(e1, v1, c11);
        }
        a0v = b0v; a1v = b1v; b0v = c0v; b1v = c1v;
        c0v = d0v; c1v = d1v; d0v = e0v; d1v = e1v;
      }
      ((float2*)&cpart[((jpar * 2 + 0) * 4 + cb) * 256])[h2] = make_float2(c00, c01);
      ((float2*)&cpart[((jpar * 2 + 1) * 4 + cb) * 256])[h2] = make_float2(c10, c11);
    }
    lds_release_bar();   // cpart ready (LDS-only boundary)

    // ===== prestage B4 chunks 0,1 (post-barrier; 32-geometry reuse safe);
    //       fold context halves -> cacb bf16 =====
    stage32(B4 + 0 * CH32, wbuf[0], wave, lane);
    stage32(B4 + 1 * CH32, wbuf[1], wave, lane);
    for (int x = tid; x < 2 * BW * HH; x += NTHR) {
      const int g = x & 255, b = (x >> 8) & 3, o = x >> 10;
      const float v = (cpart[((0 * 2 + o) * 4 + b) * 256 + g] +
                       cpart[((1 * 2 + o) * 4 + b) * 256 + g]) *
                      sinv_s[b * 2 + o];
      cacb[(o * 4 + b) * 264 + g] = f2bf(v);
    }
    lds_release_bar();   // cacb ready; B4 prefetch stays in flight

    // ===== G4: B4 chunks 0-7 -> new carry =====
    {
      f4 acc = {0, 0, 0, 0};
#pragma unroll
      for (int cc = 0; cc < 8; ++cc) {
        wait_vm(cc < 7 ? 2 : 0);
        const unsigned short* wb = wbuf[cc & 1];
        bfrag a0f, a1f;
        if (col < 8) {
          a0f = (cc < 4) ? *(const bfrag*)&cacb[col * 264 + cc * 64 + q * 8]
                         : *(const bfrag*)&hnb[col * 264 + (cc - 4) * 64 + q * 8];
          a1f = (cc < 4) ? *(const bfrag*)&cacb[col * 264 + cc * 64 + 32 + q * 8]
                         : *(const bfrag*)&hnb[col * 264 + (cc - 4) * 64 + 32 + q * 8];
        } else { a0f = zero_frag(); a1f = zero_frag(); }
        const bfrag g0 = *(const bfrag*)&wb[(wave * 2 + 0) * 512 + lane * 8];
        const bfrag g1 = *(const bfrag*)&wb[(wave * 2 + 1) * 512 + lane * 8];
        acc = mfma16(a0f, g0, acc);
        acc = mfma16(a1f, g1, acc);
        __builtin_amdgcn_sched_barrier(0);
        if (cc + 2 < 8) stage32(B4 + (cc + 2) * CH32, wbuf[cc & 1], wave, lane);
      }
      if (lane < 32) {
#pragma unroll
        for (int reg = 0; reg < 4; reg++) {
          const int m = q * 4 + reg;   // 0..7 = o*4+b
          const float v = acc[reg] + fcb;
          hf[m * 260 + nm0] = v;
          hb[m * 264 + nm0] = f2bf(v);
        }
      }
    }
    lds_release_bar();   // hb/hf ready; ALL waves past G4 reads (32->48 geometry change)
    // prestage next step's G1 chunks 0,1 (post-barrier; survives loop bottom)
    if (i + 1 < TT) {
      stage48(SR + 0 * CH48, wbuf[0], wave, lane);
      stage48(SR + 1 * CH48, wbuf[1], wave, lane);
    }
  }
}

__global__ __launch_bounds__(256) void final_combine(const float* __restrict__ ws_p,
                                                     const float* __restrict__ out_b,
                                                     float* __restrict__ out) {
  const int gidx = blockIdx.x * blockDim.x + threadIdx.x;
  if (gidx >= BATCH * TT) return;
  const int b = gidx >> 6;
  const int t = gidx & 63;
  const int idx = (t >= TT - DD - 1) ? (TT - 1) : (t + DD);
  const float* p1 = ws_p;
  const float* p2 = ws_p + (size_t)BATCH * TT;
  const float v = p1[(size_t)b * TT + t] + p2[(size_t)b * TT + idx] + out_b[0];
  out[gidx] = 1.0f / (1.0f + __expf(-v));
}

extern "C" void kernel_launch(void* const* d_in, const int* in_sizes, int n_in,
                              void* d_out, int out_size, void* d_ws, size_t ws_size,
                              hipStream_t stream) {
  const float* received = (const float*)d_in[0];
  const float* g1_Wih0 = (const float*)d_in[1];
  const float* g1_Whh0 = (const float*)d_in[2];
  const float* g1_bih0 = (const float*)d_in[3];
  const float* g1_bhh0 = (const float*)d_in[4];
  const float* g1_Wih1 = (const float*)d_in[5];
  const float* g1_Whh1 = (const float*)d_in[6];
  const float* g1_bih1 = (const float*)d_in[7];
  const float* g1_bhh1 = (const float*)d_in[8];
  const float* g2_Wih0 = (const float*)d_in[9];
  const float* g2_Whh0 = (const float*)d_in[10];
  const float* g2_bih0 = (const float*)d_in[11];
  const float* g2_bhh0 = (const float*)d_in[12];
  const float* g2_Wih1 = (const float*)d_in[13];
  const float* g2_Whh1 = (const float*)d_in[14];
  const float* g2_bih1 = (const float*)d_in[15];
  const float* g2_bhh1 = (const float*)d_in[16];
  const float* fc_W   = (const float*)d_in[17];
  const float* fc_b   = (const float*)d_in[18];
  const float* attn_W = (const float*)d_in[19];
  const float* v_W    = (const float*)d_in[20];
  const float* out_W  = (const float*)d_in[21];
  const float* out_b  = (const float*)d_in[22];

  // ws layout: fp32 pp[2*B*T] | bf16 buf[2*B*T*2*H] | bf16 ehb[same] | bf16 wf[WF_TOTAL]
  float* ws_p = (float*)d_ws;
  unsigned short* buf = (unsigned short*)(ws_p + 2 * BATCH * TT);
  unsigned short* ehb = buf + (size_t)2 * BATCH * TT * 2 * HH;
  unsigned short* wf  = ehb + (size_t)2 * BATCH * TT * 2 * HH;

  hipLaunchKernelGGL(prep_weights, dim3((WF_TOTAL + 255) / 256), dim3(256), 0, stream,
                     g1_Whh0, g1_Wih1, g1_Whh1, g2_Whh0, g2_Wih1, g2_Whh1,
                     attn_W, fc_W, wf);

  hipLaunchKernelGGL(gru_attn, dim3(NBLK), dim3(NTHR), 0, stream,
                     received,
                     g1_Wih0, g1_bih0, g1_bhh0, g1_bih1, g1_bhh1,
                     g2_Wih0, g2_bih0, g2_bhh0, g2_bih1, g2_bhh1,
                     fc_b, v_W, out_W, wf, buf, ehb, ws_p);

  hipLaunchKernelGGL(final_combine, dim3((BATCH * TT + 255) / 256), dim3(256), 0, stream,
                     ws_p, out_b, (float*)d_out);
}